// Round 5
// baseline (271.101 us; speedup 1.0000x reference)
//
#include <hip/hip_runtime.h>
#include <math.h>

#define DEV __device__ __forceinline__

typedef __attribute__((ext_vector_type(8))) short short8;
typedef __attribute__((ext_vector_type(4))) float f32x4;

DEV float sigmoidf_(float x){ return 1.f/(1.f+__expf(-x)); }
DEV float siluf_(float x){ return x/(1.f+__expf(-x)); }
DEV float softplusf_(float x){ return (x>20.f)? x : log1pf(__expf(x)); }

DEV short bf16rne(float f){
  unsigned u=__float_as_uint(f);
  unsigned r=(u + 0x7FFFu + ((u>>16)&1u))>>16;
  return (short)r;
}
DEV unsigned short bf16u(float f){ return (unsigned short)bf16rne(f); }
DEV float b2f(unsigned short u){ return __uint_as_float(((unsigned)u)<<16); }

// row index remap: mode 0 identity; mode 1 mamba interleave/deinterleave;
// mode 2 shifted-window gather/scatter (roll -4,-4 then 8x8 windows)
DEV int map_row(int r, int mode){
  if(mode==1){
    int b=r/4608; int gl=r-b*4608;
    return ((gl&1)*2+b)*2304 + (gl>>1);
  }
  if(mode==2){
    int widx=r>>6, n=r&63;
    int b=widx/36, t=widx-b*36;
    int wi=t/6, wj=t-wi*6;
    int h2=wi*8+(n>>3), w2=wj*8+(n&7);
    int ho=h2+4; if(ho>=48) ho-=48;
    int wo=w2+4; if(wo>=48) wo-=48;
    return b*2304 + ho*48 + wo;
  }
  return r;
}

// ---------------- weight fp32 -> bf16 pre-convert (7 segments, dims hardcoded) ----------------
__global__ __launch_bounds__(256) void k_w2b(const float* __restrict__ w0,const float* __restrict__ w1,
    const float* __restrict__ w2,const float* __restrict__ w3,const float* __restrict__ w4,
    const float* __restrict__ w5,const float* __restrict__ w6, short* __restrict__ dst){
  int seg=blockIdx.y;
  int i=blockIdx.x*256+threadIdx.x;
  const float* src; int size, off;
  switch(seg){
    case 0: src=w0; size=173184; off=0;      break;  // in_w 902x192
    case 1: src=w1; size=110592; off=173184; break;  // qkv 576x192
    case 2: src=w2; size=73728;  off=283776; break;  // out_w 192x384
    case 3: src=w3; size=36864;  off=357504; break;  // proj 192x192
    case 4: src=w4; size=73728;  off=394368; break;  // fus 192x384
    case 5: src=w5; size=147456; off=468096; break;  // fc1 768x192
    default:src=w6; size=147456; off=615552; break;  // fc2 192x768
  }
  if(i<size) dst[off+i]=bf16rne(src[i]);
}

// ---------------- LayerNorm over C=192 -> bf16 out ----------------
__global__ __launch_bounds__(256) void k_ln(const float* __restrict__ in, const float* __restrict__ w,
                                            const float* __restrict__ b, short* __restrict__ out){
  int warp=threadIdx.x>>6, lane=threadIdx.x&63;
  int row=blockIdx.x*4+warp;
  const float* ip=in+(size_t)row*192;
  float v0=ip[lane], v1=ip[lane+64], v2=ip[lane+128];
  float s=v0+v1+v2, sq=v0*v0+v1*v1+v2*v2;
  #pragma unroll
  for(int off=32;off;off>>=1){ s+=__shfl_xor(s,off); sq+=__shfl_xor(sq,off); }
  float mean=s*(1.f/192.f), var=sq*(1.f/192.f)-mean*mean;
  float inv=rsqrtf(var+1e-5f);
  short* op=out+(size_t)row*192;
  op[lane]    =bf16rne((v0-mean)*inv*w[lane]    +b[lane]);
  op[lane+64] =bf16rne((v1-mean)*inv*w[lane+64] +b[lane+64]);
  op[lane+128]=bf16rne((v2-mean)*inv*w[lane+128]+b[lane+128]);
}

// ---------------- bf16 GEMM, A direct-from-global, B (weights) full-chunk LDS ----------------
// Out[map_s(m)][col_off+n] = A[map_g(m)]·W[n]^T ; K multiple of 192.
// epi: 0 none/bias, 2 bias+gelu, 3 bias+res. Writes Ob (bf16) if non-null else Of (fp32).
template<int BM>
__global__ __launch_bounds__(256) void k_gemm_bf(const short* __restrict__ A, const short* __restrict__ W,
    const float* __restrict__ bias, const float* __restrict__ res,
    float* __restrict__ Of, short* __restrict__ Ob,
    int N, int K, int lda, int ldo, int col_off, int gmode, int smode, int epi){
  constexpr int MREP = BM/32;
  __shared__ short sB[64][200];           // 25 KB, 2-way-conflict reads (free)
  int tid=threadIdx.x, lane=tid&63, wid=tid>>6;
  int wr=wid>>1, wc=wid&1;
  int m16=lane&15, kq=lane>>4;
  int bm=blockIdx.y*BM, bn=blockIdx.x*64;
  const short* Arow[MREP];
  #pragma unroll
  for(int mi=0;mi<MREP;mi++){
    int m=bm + wr*(BM/2) + mi*16 + m16;
    Arow[mi]=A+(size_t)map_row(m,gmode)*lda + kq*8;
  }
  f32x4 acc[MREP][2];
  #pragma unroll
  for(int mi=0;mi<MREP;mi++)
    #pragma unroll
    for(int ni=0;ni<2;ni++) acc[mi][ni]=(f32x4){0.f,0.f,0.f,0.f};
  int nchunks=K/192;
  for(int kc=0;kc<nchunks;kc++){
    if(kc) __syncthreads();
    // stage B chunk: 64 rows x 192 bf16, 16B/lane x6 rounds
    for(int i=tid;i<1536;i+=256){
      int n=i/24, c=i-24*(i/24);
      short8 v={0,0,0,0,0,0,0,0};
      if(bn+n<N) v=*(const short8*)(W+(size_t)(bn+n)*K + kc*192 + c*8);
      *(short8*)&sB[n][c*8]=v;
    }
    __syncthreads();
    #pragma unroll
    for(int ks=0;ks<6;ks++){
      short8 af[MREP], bfr[2];
      #pragma unroll
      for(int mi=0;mi<MREP;mi++) af[mi]=*(const short8*)(Arow[mi] + kc*192 + ks*32);
      #pragma unroll
      for(int ni=0;ni<2;ni++) bfr[ni]=*(const short8*)&sB[wc*32+ni*16+m16][ks*32+kq*8];
      #pragma unroll
      for(int mi=0;mi<MREP;mi++)
        #pragma unroll
        for(int ni=0;ni<2;ni++)
          acc[mi][ni]=__builtin_amdgcn_mfma_f32_16x16x32_bf16(af[mi],bfr[ni],acc[mi][ni],0,0,0);
    }
  }
  #pragma unroll
  for(int mi=0;mi<MREP;mi++){
    #pragma unroll
    for(int r=0;r<4;r++){
      int m=bm + wr*(BM/2) + mi*16 + 4*kq + r;
      int orow=map_row(m,smode);
      const float* rp=res? res+(size_t)orow*ldo : nullptr;
      #pragma unroll
      for(int ni=0;ni<2;ni++){
        int nn=bn + wc*32 + ni*16 + m16;
        if(nn<N){
          float val=acc[mi][ni][r];
          if(bias) val+=bias[nn];
          if(epi==2) val=0.5f*val*(1.f+erff(val*0.70710678118654752f));
          else if(epi==3) val+=rp[nn];
          size_t oi=(size_t)orow*ldo+col_off+nn;
          if(Ob) Ob[oi]=bf16rne(val);
          else   Of[oi]=val;
        }
      }
    }
  }
}

// ---------------- causal depthwise conv4 + bias + silu over zx cols [384,896) ----------------
__global__ __launch_bounds__(256) void k_conv(const float* __restrict__ zx, const float* __restrict__ cw,
                       const float* __restrict__ cb, float* __restrict__ xbc){
  int e=blockIdx.x*256+threadIdx.x;
  if(e>=2*4608*512) return;
  int ch=e&511; int rl=e>>9;
  int l=rl%4608;
  float acc=cb[ch];
  const float* base=zx+(size_t)rl*902+384+ch;
  float w0=cw[ch*4],w1=cw[ch*4+1],w2=cw[ch*4+2],w3=cw[ch*4+3];
  if(l>=3) acc+=base[-3*902]*w0;
  if(l>=2) acc+=base[-2*902]*w1;
  if(l>=1) acc+=base[-902]*w2;
  acc+=base[0]*w3;
  xbc[e]=siluf_(acc);
}

// ---------------- dt softplus, a = dt*(-exp(A_log)), per-chunk inclusive cumsum ----------------
__global__ __launch_bounds__(128) void k_prep(const float* __restrict__ zx, const float* __restrict__ dt_bias,
    const float* __restrict__ A_log, float* __restrict__ dtb, float* __restrict__ acs, float* __restrict__ csum){
  int bid=blockIdx.x;
  int c=bid%36, h=(bid/36)%6, b=bid/216;
  int l=threadIdx.x;
  int row=b*4608+c*128+l;
  float xv=zx[(size_t)row*902+896+h]+dt_bias[h];
  float dt=softplusf_(xv);
  float a=-__expf(A_log[h])*dt;
  dtb[row*6+h]=dt;
  __shared__ float sb[128];
  sb[l]=a; __syncthreads();
  for(int off=1;off<128;off<<=1){
    float add=(l>=off)? sb[l-off]:0.f;
    __syncthreads();
    sb[l]+=add;
    __syncthreads();
  }
  acs[((size_t)(b*6+h)*36+c)*128+l]=sb[l];
  if(l==127) csum[(b*6+h)*36+c]=sb[127];
}

// ---------------- fused SSD part A (MFMA): states + diagonal Y ----------------
__global__ __launch_bounds__(256) void k_ssd_a(const float* __restrict__ xbc, const float* __restrict__ dtb,
    const float* __restrict__ acs, const float* __restrict__ csum,
    float* __restrict__ st, float* __restrict__ Y){
  int bid=blockIdx.x;
  int h=bid%6, c=(bid/6)%36, b=bid/216;
  __shared__ unsigned short sB[128][68];
  __shared__ unsigned short sC[128][68];
  __shared__ unsigned short sXdT[64][132];
  __shared__ unsigned short sBTE[64][132];
  __shared__ unsigned short sM[128][36];
  __shared__ float sAcs[128];
  __shared__ float sE[128];
  int tid=threadIdx.x;
  int lane=tid&63, wid=tid>>6;
  int m16=lane&15, kq=lane>>4;
  int base_row=b*4608+c*128;
  const float* acsp=acs+((size_t)(b*6+h)*36+c)*128;
  float tot=csum[(b*6+h)*36+c];
  if(tid<128){ float a=acsp[tid]; sAcs[tid]=a; sE[tid]=__expf(tot-a); }
  __syncthreads();
  for(int i=tid;i<8192;i+=256){
    int l=i>>6, n=i&63;
    int row=base_row+l;
    float Bv=xbc[(size_t)row*512+384+n];
    float Cv=xbc[(size_t)row*512+448+n];
    float Xv=xbc[(size_t)row*512+h*64+n]*dtb[row*6+h];
    sB[l][n]=bf16u(Bv);
    sC[l][n]=bf16u(Cv);
    sXdT[n][l]=bf16u(Xv);
    sBTE[n][l]=bf16u(Bv*sE[l]);
  }
  __syncthreads();
  {
    int wr=wid>>1, wc=wid&1;
    f32x4 accS[2][2];
    #pragma unroll
    for(int mi=0;mi<2;mi++)
      #pragma unroll
      for(int ni=0;ni<2;ni++) accS[mi][ni]=(f32x4){0.f,0.f,0.f,0.f};
    #pragma unroll
    for(int ks=0;ks<4;ks++){
      short8 a0=*(const short8*)&sXdT[wr*32+m16][ks*32+kq*8];
      short8 a1=*(const short8*)&sXdT[wr*32+16+m16][ks*32+kq*8];
      short8 b0=*(const short8*)&sBTE[wc*32+m16][ks*32+kq*8];
      short8 b1=*(const short8*)&sBTE[wc*32+16+m16][ks*32+kq*8];
      accS[0][0]=__builtin_amdgcn_mfma_f32_16x16x32_bf16(a0,b0,accS[0][0],0,0,0);
      accS[0][1]=__builtin_amdgcn_mfma_f32_16x16x32_bf16(a0,b1,accS[0][1],0,0,0);
      accS[1][0]=__builtin_amdgcn_mfma_f32_16x16x32_bf16(a1,b0,accS[1][0],0,0,0);
      accS[1][1]=__builtin_amdgcn_mfma_f32_16x16x32_bf16(a1,b1,accS[1][1],0,0,0);
    }
    float* op=st+((size_t)((b*36+c)*6+h))*4096;
    #pragma unroll
    for(int mi=0;mi<2;mi++)
      #pragma unroll
      for(int ni=0;ni<2;ni++)
        #pragma unroll
        for(int r=0;r<4;r++){
          int p=wr*32+mi*16+4*kq+r, n=wc*32+ni*16+m16;
          op[p*64+n]=accS[mi][ni][r];
        }
  }
  #pragma unroll
  for(int ti=0;ti<2;ti++){
    int t = ti? (7-wid) : wid;
    f32x4 accY[4];
    #pragma unroll
    for(int pi=0;pi<4;pi++) accY[pi]=(f32x4){0.f,0.f,0.f,0.f};
    int nslab=(t>>1)+1;
    for(int jt=0;jt<nslab;jt++){
      f32x4 accD[2];
      accD[0]=(f32x4){0.f,0.f,0.f,0.f}; accD[1]=(f32x4){0.f,0.f,0.f,0.f};
      #pragma unroll
      for(int ks=0;ks<2;ks++){
        short8 a =*(const short8*)&sC[t*16+m16][ks*32+kq*8];
        short8 b0=*(const short8*)&sB[jt*32+m16][ks*32+kq*8];
        short8 b1=*(const short8*)&sB[jt*32+16+m16][ks*32+kq*8];
        accD[0]=__builtin_amdgcn_mfma_f32_16x16x32_bf16(a,b0,accD[0],0,0,0);
        accD[1]=__builtin_amdgcn_mfma_f32_16x16x32_bf16(a,b1,accD[1],0,0,0);
      }
      int lrow=t*16+4*kq;
      #pragma unroll
      for(int sti=0;sti<2;sti++)
        #pragma unroll
        for(int r=0;r<4;r++){
          int l=lrow+r, s=jt*32+sti*16+m16;
          float v=(s<=l)? __expf(sAcs[l]-sAcs[s])*accD[sti][r] : 0.f;
          sM[l][sti*16+m16]=bf16u(v);
        }
      short8 am=*(const short8*)&sM[t*16+m16][kq*8];
      #pragma unroll
      for(int pi=0;pi<4;pi++){
        short8 bx=*(const short8*)&sXdT[pi*16+m16][jt*32+kq*8];
        accY[pi]=__builtin_amdgcn_mfma_f32_16x16x32_bf16(am,bx,accY[pi],0,0,0);
      }
    }
    #pragma unroll
    for(int pi=0;pi<4;pi++)
      #pragma unroll
      for(int r=0;r<4;r++){
        int l=t*16+4*kq+r, p=pi*16+m16;
        Y[(size_t)(base_row+l)*384+h*64+p]=accY[pi][r];
      }
  }
}

// ---------------- sequential chunk scan (prefetched) ----------------
__global__ __launch_bounds__(256) void k_scan(const float* __restrict__ st, const float* __restrict__ csum,
                                              float* __restrict__ prevb){
  int bid=blockIdx.x;
  int seg=bid&15, bh=bid>>4;
  int b=bh/6, h=bh%6;
  __shared__ float sE[36];
  if(threadIdx.x<36) sE[threadIdx.x]=__expf(csum[(b*6+h)*36+threadIdx.x]);
  __syncthreads();
  int e=seg*256+threadIdx.x;
  size_t stride=(size_t)6*4096;
  size_t idx=((size_t)((b*36+0)*6+h))*4096+e;
  float carry=0.f;
  float nxt=st[idx];
  for(int c=0;c<36;c++){
    float cur=nxt;
    if(c<35) nxt=st[idx+stride];
    prevb[idx]=carry;
    carry=carry*sE[c]+cur;
    idx+=stride;
  }
}

// ---------------- SSD part B (MFMA): Y += exp(acs[l])*(C_l · prev[p]) + xp*D[h] ----------------
__global__ __launch_bounds__(256) void k_ssd_b(const float* __restrict__ xbc, const float* __restrict__ prevb,
    const float* __restrict__ acs, const float* __restrict__ Dv, float* __restrict__ Y){
  int bid=blockIdx.x;
  int h=bid%6, c=(bid/6)%36, b=bid/216;
  __shared__ unsigned short sC[128][68];
  __shared__ unsigned short sP[64][68];
  __shared__ float sAcs[128];
  int tid=threadIdx.x;
  int lane=tid&63, wid=tid>>6;
  int m16=lane&15, kq=lane>>4;
  int base_row=b*4608+c*128;
  const float* acsp=acs+((size_t)(b*6+h)*36+c)*128;
  if(tid<128) sAcs[tid]=acsp[tid];
  for(int i=tid;i<8192;i+=256){ int l=i>>6,n=i&63; sC[l][n]=bf16u(xbc[(size_t)(base_row+l)*512+448+n]); }
  const float* pp=prevb+((size_t)((b*36+c)*6+h))*4096;
  for(int i=tid;i<4096;i+=256){ int p_=i>>6,n=i&63; sP[p_][n]=bf16u(pp[i]); }
  __syncthreads();
  float Dh=Dv[h];
  int lt0=2*wid;
  f32x4 acc[2][4];
  #pragma unroll
  for(int li=0;li<2;li++)
    #pragma unroll
    for(int pi=0;pi<4;pi++) acc[li][pi]=(f32x4){0.f,0.f,0.f,0.f};
  #pragma unroll
  for(int ks=0;ks<2;ks++){
    short8 a0=*(const short8*)&sC[lt0*16+m16][ks*32+kq*8];
    short8 a1=*(const short8*)&sC[(lt0+1)*16+m16][ks*32+kq*8];
    #pragma unroll
    for(int pi=0;pi<4;pi++){
      short8 bp=*(const short8*)&sP[pi*16+m16][ks*32+kq*8];
      acc[0][pi]=__builtin_amdgcn_mfma_f32_16x16x32_bf16(a0,bp,acc[0][pi],0,0,0);
      acc[1][pi]=__builtin_amdgcn_mfma_f32_16x16x32_bf16(a1,bp,acc[1][pi],0,0,0);
    }
  }
  #pragma unroll
  for(int li=0;li<2;li++){
    #pragma unroll
    for(int r=0;r<4;r++){
      int l=(lt0+li)*16+4*kq+r;
      int row=base_row+l;
      float e=__expf(sAcs[l]);
      #pragma unroll
      for(int pi=0;pi<4;pi++){
        int p=pi*16+m16;
        size_t yi=(size_t)row*384+h*64+p;
        float xpv=xbc[(size_t)row*512+h*64+p];
        Y[yi]+=acc[li][pi][r]*e+xpv*Dh;
      }
    }
  }
}

// ---------------- y = Y * silu(z), RMSNorm * norm_w -> bf16 ----------------
__global__ __launch_bounds__(256) void k_rmsgate(const float* __restrict__ Y, const float* __restrict__ zx,
    const float* __restrict__ nw, short* __restrict__ yn){
  int warp=threadIdx.x>>6, lane=threadIdx.x&63;
  int row=blockIdx.x*4+warp;
  float v[6]; float ss=0.f;
  #pragma unroll
  for(int j=0;j<6;j++){
    int cidx=lane+64*j;
    float y=Y[(size_t)row*384+cidx];
    float z=zx[(size_t)row*902+cidx];
    y*=siluf_(z);
    v[j]=y; ss+=y*y;
  }
  #pragma unroll
  for(int off=32;off;off>>=1) ss+=__shfl_xor(ss,off);
  float sc=rsqrtf(ss*(1.f/384.f)+1e-5f);
  #pragma unroll
  for(int j=0;j<6;j++){
    int cidx=lane+64*j;
    yn[(size_t)row*384+cidx]=bf16rne(v[j]*sc*nw[cidx]);
  }
}

// ---------------- windowed attention core (bf16 qkv/xn in, bf16 out) ----------------
__global__ __launch_bounds__(64) void k_att2(const short* __restrict__ qkv, const short* __restrict__ xn,
    const float* __restrict__ gw, const float* __restrict__ gb, short* __restrict__ obuf){
  int bid=blockIdx.x;
  int widx=bid/6, head=bid-widx*6;
  int b=widx/36, t=widx-b*36;
  int wi=t/6, wj=t-wi*6;
  int n=threadIdx.x;
  __shared__ float sK[64][32], sV[64][32], sS[64][65];
  size_t qbase=(size_t)(widx*64+n)*576;
  float q[32];
  #pragma unroll
  for(int d=0;d<32;d++){
    q[d]=b2f((unsigned short)qkv[qbase+head*32+d]);
    sK[n][d]=b2f((unsigned short)qkv[qbase+192+head*32+d]);
    sV[n][d]=b2f((unsigned short)qkv[qbase+384+head*32+d]);
  }
  int h2=wi*8+(n>>3), w2=wj*8+(n&7);
  int rh=(h2<40)?0:((h2<44)?1:2);
  int rw=(w2<40)?0:((w2<44)?1:2);
  int myid=rh*3+rw;
  __syncthreads();
  const float scale=0.17677669529663687f;
  for(int j=0;j<64;j++){
    float sc=0;
    #pragma unroll
    for(int d=0;d<32;d++) sc+=q[d]*sK[j][d];
    int hj=wi*8+(j>>3), wjj=wj*8+(j&7);
    int rhj=(hj<40)?0:((hj<44)?1:2);
    int rwj=(wjj<40)?0:((wjj<44)?1:2);
    float m=((rhj*3+rwj)!=myid)? -100.f:0.f;
    sS[n][j]=sc*scale+m;
  }
  float mx=-1e30f;
  for(int j=0;j<64;j++) mx=fmaxf(mx,sS[n][j]);
  float den=0;
  for(int j=0;j<64;j++){ float p=__expf(sS[n][j]-mx); sS[n][j]=p; den+=p; }
  float o[32];
  #pragma unroll
  for(int d=0;d<32;d++) o[d]=0.f;
  for(int j=0;j<64;j++){
    float p=sS[n][j];
    #pragma unroll
    for(int d=0;d<32;d++) o[d]+=p*sV[j][d];
  }
  int xrow=map_row(widx*64+n,2);
  const short* xp=xn+(size_t)xrow*192;
  const float* gwp=gw+head*192;
  float g=0;
  for(int cidx=0;cidx<192;cidx++) g+=b2f((unsigned short)xp[cidx])*gwp[cidx];
  g=sigmoidf_(g+gb[head]);
  float fac=g/den;
  short* op=obuf+(size_t)(widx*64+n)*192+head*32;
  #pragma unroll
  for(int d=0;d<32;d++) op[d]=bf16rne(o[d]*fac);
}

// ---------------- ECA pooling ----------------
__global__ __launch_bounds__(192) void k_pool1(const float* __restrict__ xf, float* __restrict__ partial){
  int bid=blockIdx.x; int b=bid/18, seg=bid%18;
  int cidx=threadIdx.x;
  const float* p=xf+((size_t)b*2304+seg*128)*192+cidx;
  float s=0;
  for(int l=0;l<128;l++) s+=p[(size_t)l*192];
  partial[bid*192+cidx]=s;
}

__global__ __launch_bounds__(768) void k_ca(const float* __restrict__ partial, const float* __restrict__ ecaw,
                                            float* __restrict__ ca){
  int tid=threadIdx.x;
  int b=tid/192, cidx=tid%192;
  float s=0;
  for(int k=0;k<18;k++) s+=partial[(b*18+k)*192+cidx];
  float pv=s*(1.f/2304.f);
  __shared__ float sP[768];
  sP[tid]=pv; __syncthreads();
  float left =(cidx>0)?   sP[tid-1]:0.f;
  float right=(cidx<191)? sP[tid+1]:0.f;
  ca[tid]=sigmoidf_(ecaw[0]*left+ecaw[1]*pv+ecaw[2]*right);
}

// ---------------- xo = x + xf * ca ----------------
__global__ __launch_bounds__(256) void k_xo(const float* __restrict__ x, const float* __restrict__ xf,
                                            const float* __restrict__ ca, float* __restrict__ xo){
  int e=blockIdx.x*256+threadIdx.x;
  if(e>=4*2304*192) return;
  int cidx=e%192;
  int b=e/(192*2304);
  xo[e]=x[e]+xf[e]*ca[b*192+cidx];
}

extern "C" void kernel_launch(void* const* d_in, const int* in_sizes, int n_in,
                              void* d_out, int out_size, void* d_ws, size_t ws_size,
                              hipStream_t stream){
  const float* x     =(const float*)d_in[0];
  const float* n1w   =(const float*)d_in[3];
  const float* n1b   =(const float*)d_in[4];
  const float* m_in_w=(const float*)d_in[5];
  const float* m_cw  =(const float*)d_in[6];
  const float* m_cb  =(const float*)d_in[7];
  const float* m_dtb =(const float*)d_in[8];
  const float* m_Al  =(const float*)d_in[9];
  const float* m_D   =(const float*)d_in[10];
  const float* m_nw  =(const float*)d_in[11];
  const float* m_ow  =(const float*)d_in[12];
  const float* qkvw  =(const float*)d_in[13];
  const float* qkvb  =(const float*)d_in[14];
  const float* projw =(const float*)d_in[15];
  const float* projb =(const float*)d_in[16];
  const float* gatew =(const float*)d_in[17];
  const float* gateb =(const float*)d_in[18];
  const float* fusw  =(const float*)d_in[19];
  const float* fusb  =(const float*)d_in[20];
  const float* ecaw  =(const float*)d_in[21];
  const float* n2w   =(const float*)d_in[22];
  const float* n2b   =(const float*)d_in[23];
  const float* fc1w  =(const float*)d_in[24];
  const float* fc1b  =(const float*)d_in[25];
  const float* fc2w  =(const float*)d_in[26];
  const float* fc2b  =(const float*)d_in[27];
  float* out=(float*)d_out;
  float* ws=(float*)d_ws;

  // fp32 arena (float offsets); bf16 buffers carved as short* aliases.
  short* xn_bf  = (short*)(ws + 0);        // 884,736 fl  [LN1 .. att2]
  short* wb     = (short*)(ws + 884736);   // 381,504 fl  persistent (bf16 weights)
  float* zx     = ws + 1266240;            // 8,312,832   [in_proj .. rmsgate]
  float* xbc    = ws + 9579072;            // 4,718,592   [conv .. ssd_b]
  float* dtb    = ws + 14297664;           //    55,296
  float* acs    = ws + 14352960;           //    55,296
  float* csum   = ws + 14408256;           //       512
  float* st     = ws + 14408768;           // 3,538,944   [ssd_a .. scan]
  float* prevb  = ws + 17947712;           // 3,538,944   [scan .. ssd_b]
  float* Y      = ws + 21486656;           // 3,538,944   [ssd_a .. rmsgate]
  float* bigbf  = ws + 25025600;           // 3,538,944   (yn_bf | qkv_bf | h1_bf)
  // aliases (disjoint lifetimes)
  short* hbuf_bf= xn_bf;                   // [LN2 .. fc1]
  short* obuf_bf= (short*)zx;              // [att2 .. proj]
  float* xf     = st;                      // [fusion .. xo]
  short* xcat_bf= (short*)prevb;           // [out_proj .. fusion]
  float* xo     = Y;                       // [xo .. fc2]
  short* yn_bf  = (short*)bigbf;           // [rmsgate .. out_proj]
  short* qkv_bf = (short*)bigbf;           // [qkv .. att2]
  short* h1_bf  = (short*)bigbf;           // [fc1 .. fc2]
  float* partial= dtb;                     // pool
  float* ca     = acs;                     // ca .. xo
  // bf16 weight segments
  short* wb_in  = wb + 0;
  short* wb_qkv = wb + 173184;
  short* wb_out = wb + 283776;
  short* wb_proj= wb + 357504;
  short* wb_fus = wb + 394368;
  short* wb_fc1 = wb + 468096;
  short* wb_fc2 = wb + 615552;

  k_w2b<<<dim3(677,7),256,0,stream>>>(m_in_w,qkvw,m_ow,projw,fusw,fc1w,fc2w,wb);
  k_ln<<<2304,256,0,stream>>>(x,n1w,n1b,xn_bf);
  // in_proj (gather: mamba interleave) -> zx fp32
  k_gemm_bf<128><<<dim3(15,72),256,0,stream>>>(xn_bf,wb_in,nullptr,nullptr,zx,nullptr, 902,192, 192,902,0, 1,0,0);
  k_conv<<<18432,256,0,stream>>>(zx,m_cw,m_cb,xbc);
  k_prep<<<432,128,0,stream>>>(zx,m_dtb,m_Al,dtb,acs,csum);
  k_ssd_a<<<432,256,0,stream>>>(xbc,dtb,acs,csum,st,Y);
  k_scan<<<192,256,0,stream>>>(st,csum,prevb);
  k_ssd_b<<<432,256,0,stream>>>(xbc,prevb,acs,m_D,Y);
  k_rmsgate<<<2304,256,0,stream>>>(Y,zx,m_nw,yn_bf);
  // mamba out_proj -> xcat[:,0:192] bf16 (scatter: de-interleave)
  k_gemm_bf<64><<<dim3(3,144),256,0,stream>>>(yn_bf,wb_out,nullptr,nullptr,nullptr,xcat_bf, 192,384, 384,384,0, 0,1,0);
  // qkv (gather: shifted windows) -> bf16
  k_gemm_bf<128><<<dim3(9,72),256,0,stream>>>(xn_bf,wb_qkv,qkvb,nullptr,nullptr,qkv_bf, 576,192, 192,576,0, 2,0,0);
  k_att2<<<864,64,0,stream>>>(qkv_bf,xn_bf,gatew,gateb,obuf_bf);
  // attn proj -> xcat[:,192:384] bf16 (scatter: reverse windows)
  k_gemm_bf<64><<<dim3(3,144),256,0,stream>>>(obuf_bf,wb_proj,projb,nullptr,nullptr,xcat_bf, 192,192, 192,384,192, 0,2,0);
  // fusion -> xf fp32
  k_gemm_bf<64><<<dim3(3,144),256,0,stream>>>(xcat_bf,wb_fus,fusb,nullptr,xf,nullptr, 192,384, 384,192,0, 0,0,0);
  k_pool1<<<72,192,0,stream>>>(xf,partial);
  k_ca<<<1,768,0,stream>>>(partial,ecaw,ca);
  k_xo<<<6912,256,0,stream>>>(x,xf,ca,xo);
  k_ln<<<2304,256,0,stream>>>(xo,n2w,n2b,hbuf_bf);
  // fc1 + gelu -> h1 bf16
  k_gemm_bf<128><<<dim3(12,72),256,0,stream>>>(hbuf_bf,wb_fc1,fc1b,nullptr,nullptr,h1_bf, 768,192, 192,768,0, 0,0,2);
  // fc2 + residual -> out fp32
  k_gemm_bf<64><<<dim3(3,144),256,0,stream>>>(h1_bf,wb_fc2,fc2b,xo,out,nullptr, 192,768, 768,192,0, 0,0,3);
}